// Round 1
// 3058.191 us; speedup vs baseline: 1.2251x; 1.2251x over previous
//
#include <hip/hip_runtime.h>

#define NT 24264
#define MT 24320      // NT padded to 128-row tiles
#define NDRUG 20000
#define NGENE 4264
#define NE 100000
#define NREL 5
#define IND 1613
#define D1 1340
#define D2 920
#define D3 740
// padded K leading dims (multiples of 32 -> whole BK tiles, 16B-aligned rows)
#define PIN 1632
#define PD1 1344
#define PD2 928
// padded N row counts for transposed-weight buffers (multiples of 128)
#define ND1 1408
#define ND2 1024
#define ND3 768

typedef unsigned short u16;
typedef unsigned int u32;
typedef short bf16x8 __attribute__((ext_vector_type(8)));
typedef float f32x4 __attribute__((ext_vector_type(4)));

__device__ __forceinline__ u16 f2bf(float f) {
  u32 u = __builtin_bit_cast(u32, f);
  u32 r = (u + 0x7FFFu + ((u >> 16) & 1u)) >> 16;  // RNE
  return (u16)r;
}
__device__ __forceinline__ float bf2f(u16 h) {
  u32 u = ((u32)h) << 16;
  return __builtin_bit_cast(float, u);
}
__device__ __forceinline__ int iclamp(int v, int lo, int hi) {
  return v < lo ? lo : (v > hi ? hi : v);
}

// direct global->LDS DMA, 16B per lane; lds dest must be wave-uniform base
__device__ __forceinline__ void gload_lds16(const u16* g, u16* l) {
  __builtin_amdgcn_global_load_lds(
      (const __attribute__((address_space(1))) unsigned int*)(const void*)g,
      (__attribute__((address_space(3))) unsigned int*)(void*)l,
      16, 0, 0);
}

// ---------------- zero int buffer ----------------
__global__ __launch_bounds__(256) void zero_i32_k(int* __restrict__ p, int n) {
  int i = blockIdx.x * 256 + threadIdx.x;
  if (i < n) p[i] = 0;
}

// ---------------- transpose f32 [K][N] -> bf16 [N][ldo], batched ----------------
__global__ __launch_bounds__(256) void transpose_k(
    const float* __restrict__ in, u16* __restrict__ out,
    int K, int N, int ldo, size_t in_batch, size_t out_batch)
{
  __shared__ u16 tile[32][33];
  const int b = blockIdx.z;
  in  += (size_t)b * in_batch;
  out += (size_t)b * out_batch;
  const int n0 = blockIdx.x * 32, k0 = blockIdx.y * 32;
  const int tx = threadIdx.x, ty = threadIdx.y;
  for (int i = ty; i < 32; i += 8) {
    int k = k0 + i, n = n0 + tx;
    tile[i][tx] = (k < K && n < N) ? f2bf(in[(size_t)k * N + n]) : (u16)0;
  }
  __syncthreads();
  for (int i = ty; i < 32; i += 8) {
    int n = n0 + i, k = k0 + tx;
    if (n < N && k < K) out[(size_t)n * ldo + k] = tile[tx][i];
  }
}

// ---------------- h0 = bf16(concat(x, gene_emb)), pad cols zeroed ----------------
__global__ __launch_bounds__(256) void build_h0_k(
    const float* __restrict__ x, const float* __restrict__ gene, u16* __restrict__ h0)
{
  const int row = blockIdx.x;
  const float* s = (row < NDRUG) ? (x + (size_t)row * IND)
                                 : (gene + (size_t)(row - NDRUG) * IND);
  u16* d = h0 + (size_t)row * PIN;
  for (int i = threadIdx.x; i < PIN; i += 256) d[i] = (i < IND) ? f2bf(s[i]) : (u16)0;
}

// ---------------- per-(relation,dst) edge counts (clamped indices) ----------------
__global__ __launch_bounds__(256) void count_k(
    const int* __restrict__ dst, const int* __restrict__ et, int* __restrict__ cnt)
{
  int e = blockIdx.x * 256 + threadIdx.x;
  if (e < NE) {
    int r = iclamp(et[e], 0, NREL - 1);
    int d = iclamp(dst[e], 0, NT - 1);
    atomicAdd(&cnt[(size_t)r * NT + d], 1);
  }
}

// ---------------- dead-simple single-block exclusive scan ----------------
__global__ __launch_bounds__(256) void scan_simple_k(
    const int* __restrict__ in, int* __restrict__ out, int n)
{
  __shared__ int part[256];
  const int tid = threadIdx.x;
  const int chunk = (n + 255) / 256;
  const int lo = tid * chunk;
  const int hi = (lo + chunk < n) ? (lo + chunk) : n;
  int s = 0;
  for (int i = lo; i < hi; ++i) s += in[i];
  part[tid] = s;
  __syncthreads();
  if (tid == 0) {
    int run = 0;
    for (int i = 0; i < 256; ++i) { int t = part[i]; part[i] = run; run += t; }
  }
  __syncthreads();
  int run = part[tid];
  for (int i = lo; i < hi; ++i) { out[i] = run; run += in[i]; }
}

// ---------------- fill CSR edge source list (clamped) ----------------
__global__ __launch_bounds__(256) void fill_k(
    const int* __restrict__ src, const int* __restrict__ dst, const int* __restrict__ et,
    const int* __restrict__ offs, int* __restrict__ pos, int* __restrict__ esrc)
{
  int e = blockIdx.x * 256 + threadIdx.x;
  if (e < NE) {
    int r = iclamp(et[e], 0, NREL - 1);
    int d = iclamp(dst[e], 0, NT - 1);
    int b = r * NT + d;
    int p = offs[b] + atomicAdd(&pos[b], 1);
    p = iclamp(p, 0, NE - 1);
    esrc[p] = iclamp(src[e], 0, NT - 1);
  }
}

// ---------------- gather-mean for one relation (bf16 H -> bf16 out) ----------------
__global__ __launch_bounds__(256) void gather_k(
    const int* __restrict__ esrc, const int* __restrict__ offs, const int* __restrict__ cnt,
    int rel, const u16* __restrict__ H, int ldh, int nvec, u16* __restrict__ out, int ldo)
{
  const int i = blockIdx.x;
  const int b = rel * NT + i;
  int n = iclamp(cnt[b], 0, NE);
  int o = iclamp(offs[b], 0, NE - 1);
  if (o + n > NE) n = NE - o;
  u16* op = out + (size_t)i * ldo;
  if (n <= 0) {
    uint4 z = {0, 0, 0, 0};
    for (int v = threadIdx.x; v < nvec; v += 256) *(uint4*)(op + v * 8) = z;
    return;
  }
  const float inv = 1.0f / (float)n;
  for (int v = threadIdx.x; v < nvec; v += 256) {
    float acc[8] = {};
    for (int e = 0; e < n; ++e) {
      int si = iclamp(esrc[o + e], 0, NT - 1);
      const u16* hp = H + (size_t)si * ldh + v * 8;
      uint4 xv = *(const uint4*)hp;
      const u16* xu = (const u16*)&xv;
      #pragma unroll
      for (int j = 0; j < 8; ++j) acc[j] += bf2f(xu[j]);
    }
    u16 r[8];
    #pragma unroll
    for (int j = 0; j < 8; ++j) {
      float f = acc[j] * inv;
      f = (f == f) ? f : 0.0f;
      r[j] = f2bf(f);
    }
    *(uint4*)(op + v * 8) = *(uint4*)r;
  }
}

// ---------------- MFMA NT-GEMM, bf16 A/B; C dtype templated ----------------
// m97-structure: 128x128 tile, BK=32, linear LDS, global_load_lds width-16 staging.
// REQUIRES: K % 32 == 0; A has >= gridDim.y*128 valid rows of lda; BT has
// >= gridDim.x*128 valid rows of ldb (pads may be garbage -> isolated to
// guarded-out C rows/cols).
// MODE 0: C = A.B + bias[col]          (init; CT=u16 bf16)
// MODE 1: C = C + A.B                  (accumulate RMW; CT=u16 bf16)
// MODE 2: C = relu(A.B + bias[col])    (final; CT=float, writes f32 emb)
template <int MODE, typename CT>
__global__ __launch_bounds__(256, 2) void gemm_nt(
    const u16* __restrict__ A, int lda,
    const u16* __restrict__ BT, int ldb,
    CT* __restrict__ C, int ldc,
    int M, int N, int K,
    const float* __restrict__ bias)
{
  constexpr int BM = 128, BN = 128, BK = 32;
  __shared__ u16 As[BM * BK];   // 8 KB, linear [row][k]
  __shared__ u16 Bs[BN * BK];   // 8 KB
  const int tid = threadIdx.x;
  const int lane = tid & 63;
  const int wid = tid >> 6;
  const int wm = wid >> 1, wn = wid & 1;  // 2x2 wave grid, 64x64 per wave
  const int q = lane >> 4, l15 = lane & 15;
  const int m0 = blockIdx.y * BM, n0 = blockIdx.x * BN;

  // staging geometry: lane l of wave w, round r covers
  //   LDS row = r*64 + w*16 + (l>>2), k-slot = (l&3)*8   (16B per lane)
  const int srow = wid * 16 + (lane >> 2);
  const int skk  = (lane & 3) * 8;
  const u16* gA0 = A  + (size_t)(m0 + srow) * lda + skk;
  const u16* gA1 = A  + (size_t)(m0 + 64 + srow) * lda + skk;
  const u16* gB0 = BT + (size_t)(n0 + srow) * ldb + skk;
  const u16* gB1 = BT + (size_t)(n0 + 64 + srow) * ldb + skk;
  u16* lA0 = &As[(size_t)(wid * 16) * BK];        // wave-uniform bases
  u16* lA1 = &As[(size_t)(64 + wid * 16) * BK];
  u16* lB0 = &Bs[(size_t)(wid * 16) * BK];
  u16* lB1 = &Bs[(size_t)(64 + wid * 16) * BK];

  f32x4 acc[4][4] = {};

  const int ktiles = K / BK;
  for (int kt = 0; kt < ktiles; ++kt) {
    gload_lds16(gA0, lA0);
    gload_lds16(gA1, lA1);
    gload_lds16(gB0, lB0);
    gload_lds16(gB1, lB1);
    gA0 += BK; gA1 += BK; gB0 += BK; gB1 += BK;
    __syncthreads();  // compiler drains vmcnt before s_barrier

    bf16x8 af[4], bfr[4];
    #pragma unroll
    for (int i = 0; i < 4; ++i)
      af[i] = *(const bf16x8*)&As[(wm * 64 + i * 16 + l15) * BK + q * 8];
    #pragma unroll
    for (int j = 0; j < 4; ++j)
      bfr[j] = *(const bf16x8*)&Bs[(wn * 64 + j * 16 + l15) * BK + q * 8];
    #pragma unroll
    for (int i = 0; i < 4; ++i)
      #pragma unroll
      for (int j = 0; j < 4; ++j)
        acc[i][j] = __builtin_amdgcn_mfma_f32_16x16x32_bf16(af[i], bfr[j], acc[i][j], 0, 0, 0);
    __syncthreads();
  }

  // epilogue: C/D layout col=lane&15, row=quad*4+reg (m89/m91-verified)
  #pragma unroll
  for (int i = 0; i < 4; ++i) {
    #pragma unroll
    for (int t = 0; t < 4; ++t) {
      const int r = m0 + wm * 64 + i * 16 + q * 4 + t;
      if (r >= M) continue;
      #pragma unroll
      for (int j = 0; j < 4; ++j) {
        const int c = n0 + wn * 64 + j * 16 + l15;
        if (c < N) {
          const size_t idx = (size_t)r * ldc + c;
          float v = acc[i][j][t];
          v = (v == v) ? v : 0.0f;  // NaN scrub
          if (MODE == 0) {
            C[idx] = (CT)f2bf(v + bias[c]);
          } else if (MODE == 1) {
            float c0 = bf2f((u16)C[idx]);
            c0 = (c0 == c0) ? c0 : 0.0f;
            C[idx] = (CT)f2bf(c0 + v);
          } else {
            float s = v + bias[c];
            s = (s > 0.0f) ? s : 0.0f;
            ((float*)C)[idx] = s;  // f32 emb write
          }
        }
      }
    }
  }
}

// ---------------- in-place relu over bf16 [NT][pad], zeroing pads ----------------
__global__ __launch_bounds__(256) void relu_pad_k(u16* __restrict__ h, int real, int pad)
{
  const int r = blockIdx.x;
  u16* p = h + (size_t)r * pad;
  for (int c = threadIdx.x; c < pad; c += 256) {
    u16 x = p[c];
    p[c] = (c < real && bf2f(x) > 0.0f) ? x : (u16)0;
  }
}

// ---------------- lin2 + log_softmax: f32 emb -> f32 logits ----------------
__global__ __launch_bounds__(256) void head_k(
    const float* __restrict__ emb,
    const float* __restrict__ w, const float* __restrict__ b, float* __restrict__ out)
{
  const int row = blockIdx.x * 4 + (threadIdx.x >> 6);
  const int lane = threadIdx.x & 63;
  if (row >= NT) return;
  const float* e = emb + (size_t)row * D3;
  float s0 = 0.f, s1 = 0.f;
  for (int k = lane; k < D3; k += 64) {
    float v = e[k];
    s0 += v * w[2 * k];
    s1 += v * w[2 * k + 1];
  }
  #pragma unroll
  for (int off = 32; off > 0; off >>= 1) {
    s0 += __shfl_down(s0, off, 64);
    s1 += __shfl_down(s1, off, 64);
  }
  if (lane == 0) {
    s0 += b[0]; s1 += b[1];
    s0 = (s0 == s0) ? s0 : 0.0f;
    s1 = (s1 == s1) ? s1 : 0.0f;
    float m = fmaxf(s0, s1);
    float lse = m + logf(expf(s0 - m) + expf(s1 - m));
    out[2 * (size_t)row]     = s0 - lse;
    out[2 * (size_t)row + 1] = s1 - lse;
  }
}

extern "C" void kernel_launch(void* const* d_in, const int* in_sizes, int n_in,
                              void* d_out, int out_size, void* d_ws, size_t ws_size,
                              hipStream_t stream)
{
  (void)in_sizes; (void)n_in; (void)out_size;
  const float* x     = (const float*)d_in[0];
  const int*   ei    = (const int*)d_in[1];
  const int*   et    = (const int*)d_in[2];
  const float* gene  = (const float*)d_in[3];
  const float* W1    = (const float*)d_in[4];
  const float* root1 = (const float*)d_in[5];
  const float* b1    = (const float*)d_in[6];
  const float* W2    = (const float*)d_in[7];
  const float* root2 = (const float*)d_in[8];
  const float* b2    = (const float*)d_in[9];
  const float* l1w   = (const float*)d_in[10];
  const float* l1b   = (const float*)d_in[11];
  const float* l2w   = (const float*)d_in[12];
  const float* l2b   = (const float*)d_in[13];
  const int* srcI = ei;
  const int* dstI = ei + NE;

  char* base = (char*)d_ws;
  size_t off = 0;
  auto take = [&](size_t bytes) -> char* {
    char* p = base + off;
    off += (bytes + 255) & ~(size_t)255;
    return p;
  };
  u16* regA = (u16*)take((size_t)MT * PIN * 2);  // h0 bf16; later layer-2 C -> h2
  u16* regB = (u16*)take((size_t)MT * PIN * 2);  // agg bf16
  u16* regC = (u16*)take((size_t)MT * PD1 * 2);  // layer-1 C bf16 -> h1
  int* cnt  = (int*)take((size_t)NREL * NT * 4);
  int* pos  = (int*)take((size_t)NREL * NT * 4);
  int* offs = (int*)take((size_t)NREL * NT * 4);
  int* esrc = (int*)take((size_t)NE * 4);
  u16* BTr1 = (u16*)take((size_t)ND1 * PIN * 2);
  u16* BTW1 = (u16*)take((size_t)NREL * ND1 * PIN * 2);
  u16* BTr2 = (u16*)take((size_t)ND2 * PD1 * 2);
  u16* BTW2 = (u16*)take((size_t)NREL * ND2 * PD1 * 2);
  u16* BTl1 = (u16*)take((size_t)ND3 * PD2 * 2);
  char* wzend = base + off;

  if (off > ws_size) return;  // signature: zero output -> absmax ~1.35

  float* outp = (float*)d_out;
  float* emb  = outp + (size_t)NT * 2;

  // ---- CSR build ----
  zero_i32_k<<<(NREL * NT + 255) / 256, 256, 0, stream>>>(cnt, NREL * NT);
  zero_i32_k<<<(NREL * NT + 255) / 256, 256, 0, stream>>>(pos, NREL * NT);
  count_k<<<(NE + 255) / 256, 256, 0, stream>>>(dstI, et, cnt);
  scan_simple_k<<<1, 256, 0, stream>>>(cnt, offs, NREL * NT);
  fill_k<<<(NE + 255) / 256, 256, 0, stream>>>(srcI, dstI, et, offs, pos, esrc);

  // ---- zero the whole transposed-weight region (covers N-pad rows) ----
  {
    size_t wzn = (size_t)(wzend - (char*)BTr1) / 4;
    zero_i32_k<<<(int)((wzn + 255) / 256), 256, 0, stream>>>((int*)BTr1, (int)wzn);
  }

  // ---- weight transposes (f32 -> bf16); K pads zero-filled by kernel ----
  dim3 tb(32, 8);
  transpose_k<<<dim3((D1 + 31) / 32, (IND + 31) / 32, 1),    tb, 0, stream>>>(root1, BTr1, IND, D1, PIN, 0, 0);
  transpose_k<<<dim3((D1 + 31) / 32, (IND + 31) / 32, NREL), tb, 0, stream>>>(W1, BTW1, IND, D1, PIN, (size_t)IND * D1, (size_t)ND1 * PIN);
  transpose_k<<<dim3((D2 + 31) / 32, (D1 + 31) / 32, 1),     tb, 0, stream>>>(root2, BTr2, D1, D2, PD1, 0, 0);
  transpose_k<<<dim3((D2 + 31) / 32, (D1 + 31) / 32, NREL),  tb, 0, stream>>>(W2, BTW2, D1, D2, PD1, (size_t)D1 * D2, (size_t)ND2 * PD1);
  transpose_k<<<dim3((D3 + 31) / 32, (D2 + 31) / 32, 1),     tb, 0, stream>>>(l1w, BTl1, D2, D3, PD2, 0, 0);

  build_h0_k<<<NT, 256, 0, stream>>>(x, gene, regA);

  // ---- layer 1: regC = h0@root1 + b1 + sum_r mean_r(h0)@W1_r ----
  dim3 g1((D1 + 127) / 128, (NT + 127) / 128);
  gemm_nt<0, u16><<<g1, 256, 0, stream>>>(regA, PIN, BTr1, PIN, regC, PD1, NT, D1, PIN, b1);
  for (int r = 0; r < NREL; ++r) {
    gather_k<<<NT, 256, 0, stream>>>(esrc, offs, cnt, r, regA, PIN, PIN / 8, regB, PIN);
    gemm_nt<1, u16><<<g1, 256, 0, stream>>>(regB, PIN, BTW1 + (size_t)r * ND1 * PIN, PIN, regC, PD1, NT, D1, PIN, nullptr);
  }
  relu_pad_k<<<NT, 256, 0, stream>>>(regC, D1, PD1);  // regC = h1

  // ---- layer 2: regA = h1@root2 + b2 + sum_r mean_r(h1)@W2_r ----
  dim3 g2((D2 + 127) / 128, (NT + 127) / 128);
  gemm_nt<0, u16><<<g2, 256, 0, stream>>>(regC, PD1, BTr2, PD1, regA, PD2, NT, D2, PD1, b2);
  for (int r = 0; r < NREL; ++r) {
    gather_k<<<NT, 256, 0, stream>>>(esrc, offs, cnt, r, regC, PD1, PD1 / 8, regB, PD1);
    gemm_nt<1, u16><<<g2, 256, 0, stream>>>(regB, PD1, BTW2 + (size_t)r * ND2 * PD1, PD1, regA, PD2, NT, D2, PD1, nullptr);
  }
  relu_pad_k<<<NT, 256, 0, stream>>>(regA, D2, PD2);  // regA = h2

  // ---- lin1 (fused bias+relu) -> f32 emb in d_out ----
  dim3 g3((D3 + 127) / 128, (NT + 127) / 128);
  gemm_nt<2, float><<<g3, 256, 0, stream>>>(regA, PD2, BTl1, PD2, emb, D3, NT, D3, PD2, l1b);

  // ---- lin2 + log_softmax (f32) ----
  head_k<<<(NT + 3) / 4, 256, 0, stream>>>(emb, l2w, l2b, outp);
}

// Round 2
// 2756.406 us; speedup vs baseline: 1.3592x; 1.1095x over previous
//
#include <hip/hip_runtime.h>

#define NT 24264
#define MT 24320      // NT padded to 128-row tiles
#define NDRUG 20000
#define NGENE 4264
#define NE 100000
#define NREL 5
#define IND 1613
#define D1 1340
#define D2 920
#define D3 740
// padded K leading dims (multiples of 32 -> whole BK tiles, 16B-aligned bf16 rows)
#define PIN 1632
#define PD1 1344
#define PD2 928
// concatenated K dims (root + 5 relations)
#define CAT1 (6 * PIN)   // 9792
#define CAT2 (6 * PD1)   // 8064
// padded N row counts for transposed-weight buffers (multiples of 128)
#define ND1 1408
#define ND2 1024
#define ND3 768

typedef unsigned short u16;
typedef unsigned int u32;
typedef short bf16x8 __attribute__((ext_vector_type(8)));
typedef float f32x4 __attribute__((ext_vector_type(4)));

__device__ __forceinline__ u16 f2bf(float f) {
  u32 u = __builtin_bit_cast(u32, f);
  u32 r = (u + 0x7FFFu + ((u >> 16) & 1u)) >> 16;  // RNE
  return (u16)r;
}
__device__ __forceinline__ float bf2f(u16 h) {
  u32 u = ((u32)h) << 16;
  return __builtin_bit_cast(float, u);
}
__device__ __forceinline__ int iclamp(int v, int lo, int hi) {
  return v < lo ? lo : (v > hi ? hi : v);
}

// direct global->LDS DMA, 16B per lane; lds dest must be wave-uniform base
__device__ __forceinline__ void gload_lds16(const u16* g, u16* l) {
  __builtin_amdgcn_global_load_lds(
      (const __attribute__((address_space(1))) unsigned int*)(const void*)g,
      (__attribute__((address_space(3))) unsigned int*)(void*)l,
      16, 0, 0);
}

// bijective XCD-aware tile swizzle (m204): consecutive linear blocks -> same XCD chunk
__device__ __forceinline__ void swz_tile(int& m0, int& n0) {
  const int gx = gridDim.x;
  const int nwg = gx * gridDim.y;
  const int orig = blockIdx.y * gx + blockIdx.x;
  const int q = nwg >> 3, rr = nwg & 7;
  const int xcd = orig & 7, idx = orig >> 3;
  const int nid = (xcd < rr ? xcd * (q + 1) : rr * (q + 1) + (xcd - rr) * q) + idx;
  m0 = (nid / gx) * 128;
  n0 = (nid % gx) * 128;
}

// ---------------- zero int buffer ----------------
__global__ __launch_bounds__(256) void zero_i32_k(int* __restrict__ p, int n) {
  int i = blockIdx.x * 256 + threadIdx.x;
  if (i < n) p[i] = 0;
}

// ---------------- zero pad columns of bf16 [rows][P], cols [D,P) ----------------
__global__ __launch_bounds__(256) void zero_pad_cols_k(u16* __restrict__ h, int D, int P, int rows) {
  int r = blockIdx.x * 256 + threadIdx.x;
  if (r < rows) {
    u16* p = h + (size_t)r * P;
    for (int c = D; c < P; ++c) p[c] = 0;
  }
}

// ---------------- transpose f32 [K][N] -> bf16 [N][ldo], batched ----------------
__global__ __launch_bounds__(256) void transpose_k(
    const float* __restrict__ in, u16* __restrict__ out,
    int K, int N, int ldo, size_t in_batch, size_t out_batch)
{
  __shared__ u16 tile[32][33];
  const int b = blockIdx.z;
  in  += (size_t)b * in_batch;
  out += (size_t)b * out_batch;
  const int n0 = blockIdx.x * 32, k0 = blockIdx.y * 32;
  const int tx = threadIdx.x, ty = threadIdx.y;
  for (int i = ty; i < 32; i += 8) {
    int k = k0 + i, n = n0 + tx;
    tile[i][tx] = (k < K && n < N) ? f2bf(in[(size_t)k * N + n]) : (u16)0;
  }
  __syncthreads();
  for (int i = ty; i < 32; i += 8) {
    int n = n0 + i, k = k0 + tx;
    if (n < N && k < K) out[(size_t)n * ldo + k] = tile[tx][i];
  }
}

// ---------------- h0 = bf16(concat(x, gene_emb)), pad cols zeroed ----------------
__global__ __launch_bounds__(256) void build_h0_k(
    const float* __restrict__ x, const float* __restrict__ gene, u16* __restrict__ h0)
{
  const int row = blockIdx.x;
  const float* s = (row < NDRUG) ? (x + (size_t)row * IND)
                                 : (gene + (size_t)(row - NDRUG) * IND);
  u16* d = h0 + (size_t)row * PIN;
  for (int i = threadIdx.x; i < PIN; i += 256) d[i] = (i < IND) ? f2bf(s[i]) : (u16)0;
}

// ---------------- per-(relation,dst) edge counts (clamped indices) ----------------
__global__ __launch_bounds__(256) void count_k(
    const int* __restrict__ dst, const int* __restrict__ et, int* __restrict__ cnt)
{
  int e = blockIdx.x * 256 + threadIdx.x;
  if (e < NE) {
    int r = iclamp(et[e], 0, NREL - 1);
    int d = iclamp(dst[e], 0, NT - 1);
    atomicAdd(&cnt[(size_t)r * NT + d], 1);
  }
}

// ---------------- dead-simple single-block exclusive scan ----------------
__global__ __launch_bounds__(256) void scan_simple_k(
    const int* __restrict__ in, int* __restrict__ out, int n)
{
  __shared__ int part[256];
  const int tid = threadIdx.x;
  const int chunk = (n + 255) / 256;
  const int lo = tid * chunk;
  const int hi = (lo + chunk < n) ? (lo + chunk) : n;
  int s = 0;
  for (int i = lo; i < hi; ++i) s += in[i];
  part[tid] = s;
  __syncthreads();
  if (tid == 0) {
    int run = 0;
    for (int i = 0; i < 256; ++i) { int t = part[i]; part[i] = run; run += t; }
  }
  __syncthreads();
  int run = part[tid];
  for (int i = lo; i < hi; ++i) { out[i] = run; run += in[i]; }
}

// ---------------- fill CSR edge source list (clamped) ----------------
__global__ __launch_bounds__(256) void fill_k(
    const int* __restrict__ src, const int* __restrict__ dst, const int* __restrict__ et,
    const int* __restrict__ offs, int* __restrict__ pos, int* __restrict__ esrc)
{
  int e = blockIdx.x * 256 + threadIdx.x;
  if (e < NE) {
    int r = iclamp(et[e], 0, NREL - 1);
    int d = iclamp(dst[e], 0, NT - 1);
    int b = r * NT + d;
    int p = offs[b] + atomicAdd(&pos[b], 1);
    p = iclamp(p, 0, NE - 1);
    esrc[p] = iclamp(src[e], 0, NT - 1);
  }
}

// ---------------- gather-mean for one relation (bf16 H -> bf16 out) ----------------
__global__ __launch_bounds__(256) void gather_k(
    const int* __restrict__ esrc, const int* __restrict__ offs, const int* __restrict__ cnt,
    int rel, const u16* __restrict__ H, int ldh, int nvec, u16* __restrict__ out, int ldo)
{
  const int i = blockIdx.x;
  const int b = rel * NT + i;
  int n = iclamp(cnt[b], 0, NE);
  int o = iclamp(offs[b], 0, NE - 1);
  if (o + n > NE) n = NE - o;
  u16* op = out + (size_t)i * ldo;
  if (n <= 0) {
    uint4 z = {0, 0, 0, 0};
    for (int v = threadIdx.x; v < nvec; v += 256) *(uint4*)(op + v * 8) = z;
    return;
  }
  const float inv = 1.0f / (float)n;
  for (int v = threadIdx.x; v < nvec; v += 256) {
    float acc[8] = {};
    for (int e = 0; e < n; ++e) {
      int si = iclamp(esrc[o + e], 0, NT - 1);
      const u16* hp = H + (size_t)si * ldh + v * 8;
      uint4 xv = *(const uint4*)hp;
      const u16* xu = (const u16*)&xv;
      #pragma unroll
      for (int j = 0; j < 8; ++j) acc[j] += bf2f(xu[j]);
    }
    u16 r[8];
    #pragma unroll
    for (int j = 0; j < 8; ++j) {
      float f = acc[j] * inv;
      f = (f == f) ? f : 0.0f;
      r[j] = f2bf(f);
    }
    *(uint4*)(op + v * 8) = *(uint4*)r;
  }
}

// ---------------- MFMA NT-GEMM, bf16 A/B; C dtype templated (fallback + lin1) ----
// MODE 0: C = A.B + bias[col]          (init; CT=u16 bf16)
// MODE 1: C = C + A.B                  (accumulate RMW; CT=u16 bf16)
// MODE 2: C = relu(A.B + bias[col])    (final; CT=float, writes f32 emb)
template <int MODE, typename CT>
__global__ __launch_bounds__(256, 2) void gemm_nt(
    const u16* __restrict__ A, int lda,
    const u16* __restrict__ BT, int ldb,
    CT* __restrict__ C, int ldc,
    int M, int N, int K,
    const float* __restrict__ bias)
{
  constexpr int BM = 128, BN = 128, BK = 32;
  __shared__ u16 As[BM * BK];
  __shared__ u16 Bs[BN * BK];
  const int tid = threadIdx.x;
  const int lane = tid & 63;
  const int wid = tid >> 6;
  const int wm = wid >> 1, wn = wid & 1;
  const int q = lane >> 4, l15 = lane & 15;
  int m0, n0;
  swz_tile(m0, n0);

  const int srow = wid * 16 + (lane >> 2);
  const int skk  = (lane & 3) * 8;
  const u16* gA0 = A  + (size_t)(m0 + srow) * lda + skk;
  const u16* gA1 = A  + (size_t)(m0 + 64 + srow) * lda + skk;
  const u16* gB0 = BT + (size_t)(n0 + srow) * ldb + skk;
  const u16* gB1 = BT + (size_t)(n0 + 64 + srow) * ldb + skk;
  u16* lA0 = &As[(size_t)(wid * 16) * BK];
  u16* lA1 = &As[(size_t)(64 + wid * 16) * BK];
  u16* lB0 = &Bs[(size_t)(wid * 16) * BK];
  u16* lB1 = &Bs[(size_t)(64 + wid * 16) * BK];

  f32x4 acc[4][4] = {};

  const int ktiles = K / BK;
  for (int kt = 0; kt < ktiles; ++kt) {
    gload_lds16(gA0, lA0);
    gload_lds16(gA1, lA1);
    gload_lds16(gB0, lB0);
    gload_lds16(gB1, lB1);
    gA0 += BK; gA1 += BK; gB0 += BK; gB1 += BK;
    __syncthreads();

    bf16x8 af[4], bfr[4];
    #pragma unroll
    for (int i = 0; i < 4; ++i)
      af[i] = *(const bf16x8*)&As[(wm * 64 + i * 16 + l15) * BK + q * 8];
    #pragma unroll
    for (int j = 0; j < 4; ++j)
      bfr[j] = *(const bf16x8*)&Bs[(wn * 64 + j * 16 + l15) * BK + q * 8];
    #pragma unroll
    for (int i = 0; i < 4; ++i)
      #pragma unroll
      for (int j = 0; j < 4; ++j)
        acc[i][j] = __builtin_amdgcn_mfma_f32_16x16x32_bf16(af[i], bfr[j], acc[i][j], 0, 0, 0);
    __syncthreads();
  }

  #pragma unroll
  for (int i = 0; i < 4; ++i) {
    #pragma unroll
    for (int t = 0; t < 4; ++t) {
      const int r = m0 + wm * 64 + i * 16 + q * 4 + t;
      if (r >= M) continue;
      #pragma unroll
      for (int j = 0; j < 4; ++j) {
        const int c = n0 + wn * 64 + j * 16 + l15;
        if (c < N) {
          const size_t idx = (size_t)r * ldc + c;
          float v = acc[i][j][t];
          v = (v == v) ? v : 0.0f;
          if (MODE == 0) {
            C[idx] = (CT)f2bf(v + bias[c]);
          } else if (MODE == 1) {
            float c0 = bf2f((u16)C[idx]);
            c0 = (c0 == c0) ? c0 : 0.0f;
            C[idx] = (CT)f2bf(c0 + v);
          } else {
            float s = v + bias[c];
            s = (s > 0.0f) ? s : 0.0f;
            ((float*)C)[idx] = s;
          }
        }
      }
    }
  }
}

// ---------------- fused K-concat GEMM: C = relu(concat(A0,A1).B + bias) -> bf16 ----
// A is virtually [M][K0 + 5*K0-ish]: k < K0 reads A0 (lda0), k >= K0 reads A1 (lda1,
// 5-slot concat). Wave-uniform slot select per K-tile. K0 % 32 == 0, Ktot % 32 == 0.
__global__ __launch_bounds__(256, 2) void gemm_cat(
    const u16* __restrict__ A0, int lda0, int K0,
    const u16* __restrict__ A1, int lda1,
    const u16* __restrict__ BT, int ldb,
    u16* __restrict__ C, int ldc,
    int M, int N, int Ktot,
    const float* __restrict__ bias)
{
  constexpr int BM = 128, BN = 128, BK = 32;
  __shared__ u16 As[BM * BK];
  __shared__ u16 Bs[BN * BK];
  const int tid = threadIdx.x;
  const int lane = tid & 63;
  const int wid = tid >> 6;
  const int wm = wid >> 1, wn = wid & 1;
  const int q = lane >> 4, l15 = lane & 15;
  int m0, n0;
  swz_tile(m0, n0);

  const int srow = wid * 16 + (lane >> 2);
  const int skk  = (lane & 3) * 8;
  const u16* a0lo = A0 + (size_t)(m0 + srow) * lda0 + skk;
  const u16* a0hi = A0 + (size_t)(m0 + 64 + srow) * lda0 + skk;
  const u16* a1lo = A1 + (size_t)(m0 + srow) * lda1 + skk;
  const u16* a1hi = A1 + (size_t)(m0 + 64 + srow) * lda1 + skk;
  const u16* b0   = BT + (size_t)(n0 + srow) * ldb + skk;
  const u16* b1p  = BT + (size_t)(n0 + 64 + srow) * ldb + skk;
  u16* lA0 = &As[(size_t)(wid * 16) * BK];
  u16* lA1 = &As[(size_t)(64 + wid * 16) * BK];
  u16* lB0 = &Bs[(size_t)(wid * 16) * BK];
  u16* lB1 = &Bs[(size_t)(64 + wid * 16) * BK];

  f32x4 acc[4][4] = {};

  const int ktiles = Ktot / BK;
  for (int kt = 0; kt < ktiles; ++kt) {
    const int k0 = kt * BK;
    const u16 *ga0, *ga1;
    if (k0 < K0) { ga0 = a0lo + k0; ga1 = a0hi + k0; }
    else         { ga0 = a1lo + (k0 - K0); ga1 = a1hi + (k0 - K0); }
    gload_lds16(ga0, lA0);
    gload_lds16(ga1, lA1);
    gload_lds16(b0 + k0, lB0);
    gload_lds16(b1p + k0, lB1);
    __syncthreads();

    bf16x8 af[4], bfr[4];
    #pragma unroll
    for (int i = 0; i < 4; ++i)
      af[i] = *(const bf16x8*)&As[(wm * 64 + i * 16 + l15) * BK + q * 8];
    #pragma unroll
    for (int j = 0; j < 4; ++j)
      bfr[j] = *(const bf16x8*)&Bs[(wn * 64 + j * 16 + l15) * BK + q * 8];
    #pragma unroll
    for (int i = 0; i < 4; ++i)
      #pragma unroll
      for (int j = 0; j < 4; ++j)
        acc[i][j] = __builtin_amdgcn_mfma_f32_16x16x32_bf16(af[i], bfr[j], acc[i][j], 0, 0, 0);
    __syncthreads();
  }

  // epilogue: relu(acc + bias) -> bf16
  #pragma unroll
  for (int i = 0; i < 4; ++i) {
    #pragma unroll
    for (int t = 0; t < 4; ++t) {
      const int r = m0 + wm * 64 + i * 16 + q * 4 + t;
      if (r >= M) continue;
      #pragma unroll
      for (int j = 0; j < 4; ++j) {
        const int c = n0 + wn * 64 + j * 16 + l15;
        if (c < N) {
          float v = acc[i][j][t];
          v = (v == v) ? v : 0.0f;
          float s = v + bias[c];
          s = (s > 0.0f) ? s : 0.0f;
          C[(size_t)r * ldc + c] = f2bf(s);
        }
      }
    }
  }
}

// ---------------- in-place relu over bf16 [NT][pad], zeroing pads (fallback) -----
__global__ __launch_bounds__(256) void relu_pad_k(u16* __restrict__ h, int real, int pad)
{
  const int r = blockIdx.x;
  u16* p = h + (size_t)r * pad;
  for (int c = threadIdx.x; c < pad; c += 256) {
    u16 x = p[c];
    p[c] = (c < real && bf2f(x) > 0.0f) ? x : (u16)0;
  }
}

// ---------------- lin2 + log_softmax: f32 emb -> f32 logits ----------------
__global__ __launch_bounds__(256) void head_k(
    const float* __restrict__ emb,
    const float* __restrict__ w, const float* __restrict__ b, float* __restrict__ out)
{
  const int row = blockIdx.x * 4 + (threadIdx.x >> 6);
  const int lane = threadIdx.x & 63;
  if (row >= NT) return;
  const float* e = emb + (size_t)row * D3;
  float s0 = 0.f, s1 = 0.f;
  for (int k = lane; k < D3; k += 64) {
    float v = e[k];
    s0 += v * w[2 * k];
    s1 += v * w[2 * k + 1];
  }
  #pragma unroll
  for (int off = 32; off > 0; off >>= 1) {
    s0 += __shfl_down(s0, off, 64);
    s1 += __shfl_down(s1, off, 64);
  }
  if (lane == 0) {
    s0 += b[0]; s1 += b[1];
    s0 = (s0 == s0) ? s0 : 0.0f;
    s1 = (s1 == s1) ? s1 : 0.0f;
    float m = fmaxf(s0, s1);
    float lse = m + logf(expf(s0 - m) + expf(s1 - m));
    out[2 * (size_t)row]     = s0 - lse;
    out[2 * (size_t)row + 1] = s1 - lse;
  }
}

extern "C" void kernel_launch(void* const* d_in, const int* in_sizes, int n_in,
                              void* d_out, int out_size, void* d_ws, size_t ws_size,
                              hipStream_t stream)
{
  (void)in_sizes; (void)n_in; (void)out_size;
  const float* x     = (const float*)d_in[0];
  const int*   ei    = (const int*)d_in[1];
  const int*   et    = (const int*)d_in[2];
  const float* gene  = (const float*)d_in[3];
  const float* W1    = (const float*)d_in[4];
  const float* root1 = (const float*)d_in[5];
  const float* b1    = (const float*)d_in[6];
  const float* W2    = (const float*)d_in[7];
  const float* root2 = (const float*)d_in[8];
  const float* b2    = (const float*)d_in[9];
  const float* l1w   = (const float*)d_in[10];
  const float* l1b   = (const float*)d_in[11];
  const float* l2w   = (const float*)d_in[12];
  const float* l2b   = (const float*)d_in[13];
  const int* srcI = ei;
  const int* dstI = ei + NE;

  char* base = (char*)d_ws;
  size_t off = 0;
  auto take = [&](size_t bytes) -> char* {
    char* p = base + off;
    off += (bytes + 255) & ~(size_t)255;
    return p;
  };
  u16* regA = (u16*)take((size_t)MT * PIN * 2);  // h0; later reused as h2
  u16* regC = (u16*)take((size_t)MT * PD1 * 2);  // h1
  int* cnt  = (int*)take((size_t)NREL * NT * 4);
  int* pos  = (int*)take((size_t)NREL * NT * 4);
  int* offs = (int*)take((size_t)NREL * NT * 4);
  int* esrc = (int*)take((size_t)NE * 4);
  char* wz0 = base + off;
  u16* BTcat1 = (u16*)take((size_t)ND1 * CAT1 * 2);  // [root1^T | W1_r^T] K-concat
  u16* BTcat2 = (u16*)take((size_t)ND2 * CAT2 * 2);  // [root2^T | W2_r^T]
  u16* BTl1   = (u16*)take((size_t)ND3 * PD2 * 2);
  char* wz1 = base + off;
  const size_t base_off = off;
  // shared tail region: fused cat buffer (5 slots) or fallback regB
  u16* bufX = (u16*)(base + base_off);
  const size_t cat_bytes  = (size_t)MT * 5 * PIN * 2;  // 397 MB (covers layer-2's 5*PD1 too)
  const size_t regb_bytes = (size_t)MT * PIN * 2;
  const bool fused = (base_off + cat_bytes) <= ws_size;
  if (!fused && (base_off + regb_bytes) > ws_size) return;  // cannot run at all

  float* outp = (float*)d_out;
  float* emb  = outp + (size_t)NT * 2;

  // ---- CSR build ----
  zero_i32_k<<<(NREL * NT + 255) / 256, 256, 0, stream>>>(cnt, NREL * NT);
  zero_i32_k<<<(NREL * NT + 255) / 256, 256, 0, stream>>>(pos, NREL * NT);
  count_k<<<(NE + 255) / 256, 256, 0, stream>>>(dstI, et, cnt);
  scan_simple_k<<<1, 256, 0, stream>>>(cnt, offs, NREL * NT);
  fill_k<<<(NE + 255) / 256, 256, 0, stream>>>(srcI, dstI, et, offs, pos, esrc);

  // ---- zero whole transposed-weight region (covers K pads + N-pad rows) ----
  {
    size_t wzn = (size_t)(wz1 - wz0) / 4;
    zero_i32_k<<<(int)((wzn + 255) / 256), 256, 0, stream>>>((int*)wz0, (int)wzn);
  }

  // ---- weight transposes (f32 -> bf16) into K-concat layout ----
  dim3 tb(32, 8);
  transpose_k<<<dim3((D1 + 31) / 32, (IND + 31) / 32, 1),    tb, 0, stream>>>(root1, BTcat1, IND, D1, CAT1, 0, 0);
  transpose_k<<<dim3((D1 + 31) / 32, (IND + 31) / 32, NREL), tb, 0, stream>>>(W1, BTcat1 + PIN, IND, D1, CAT1, (size_t)IND * D1, (size_t)PIN);
  transpose_k<<<dim3((D2 + 31) / 32, (D1 + 31) / 32, 1),     tb, 0, stream>>>(root2, BTcat2, D1, D2, CAT2, 0, 0);
  transpose_k<<<dim3((D2 + 31) / 32, (D1 + 31) / 32, NREL),  tb, 0, stream>>>(W2, BTcat2 + PD1, D1, D2, CAT2, (size_t)D1 * D2, (size_t)PD1);
  transpose_k<<<dim3((D3 + 31) / 32, (D2 + 31) / 32, 1),     tb, 0, stream>>>(l1w, BTl1, D2, D3, PD2, 0, 0);

  build_h0_k<<<NT, 256, 0, stream>>>(x, gene, regA);

  dim3 g1((D1 + 127) / 128, (MT + 127) / 128);
  dim3 g2((D2 + 127) / 128, (MT + 127) / 128);
  dim3 g3((D3 + 127) / 128, (MT + 127) / 128);

  if (fused) {
    // ---- layer 1: h1 = relu([h0 | agg0..agg4] @ [root1;W1] + b1), one GEMM ----
    for (int r = 0; r < NREL; ++r)
      gather_k<<<NT, 256, 0, stream>>>(esrc, offs, cnt, r, regA, PIN, PIN / 8, bufX + (size_t)r * PIN, 5 * PIN);
    gemm_cat<<<g1, 256, 0, stream>>>(regA, PIN, PIN, bufX, 5 * PIN, BTcat1, CAT1, regC, PD1, NT, D1, CAT1, b1);
    zero_pad_cols_k<<<(NT + 255) / 256, 256, 0, stream>>>(regC, D1, PD1, NT);

    // ---- layer 2: h2 = relu([h1 | agg0..agg4] @ [root2;W2] + b2), one GEMM ----
    for (int r = 0; r < NREL; ++r)
      gather_k<<<NT, 256, 0, stream>>>(esrc, offs, cnt, r, regC, PD1, PD1 / 8, bufX + (size_t)r * PD1, 5 * PD1);
    gemm_cat<<<g2, 256, 0, stream>>>(regC, PD1, PD1, bufX, 5 * PD1, BTcat2, CAT2, regA, PD2, NT, D2, CAT2, b2);
    zero_pad_cols_k<<<(NT + 255) / 256, 256, 0, stream>>>(regA, D2, PD2, NT);
  } else {
    // ---- fallback: verified 6-GEMM-per-layer path (bufX = regB) ----
    u16* regB = bufX;
    gemm_nt<0, u16><<<g1, 256, 0, stream>>>(regA, PIN, BTcat1, CAT1, regC, PD1, NT, D1, PIN, b1);
    for (int r = 0; r < NREL; ++r) {
      gather_k<<<NT, 256, 0, stream>>>(esrc, offs, cnt, r, regA, PIN, PIN / 8, regB, PIN);
      gemm_nt<1, u16><<<g1, 256, 0, stream>>>(regB, PIN, BTcat1 + (size_t)(r + 1) * PIN, CAT1, regC, PD1, NT, D1, PIN, nullptr);
    }
    relu_pad_k<<<NT, 256, 0, stream>>>(regC, D1, PD1);

    gemm_nt<0, u16><<<g2, 256, 0, stream>>>(regC, PD1, BTcat2, CAT2, regA, PD2, NT, D2, PD1, b2);
    for (int r = 0; r < NREL; ++r) {
      gather_k<<<NT, 256, 0, stream>>>(esrc, offs, cnt, r, regC, PD1, PD1 / 8, regB, PD1);
      gemm_nt<1, u16><<<g2, 256, 0, stream>>>(regB, PD1, BTcat2 + (size_t)(r + 1) * PD1, CAT2, regA, PD2, NT, D2, PD1, nullptr);
    }
    relu_pad_k<<<NT, 256, 0, stream>>>(regA, D2, PD2);
  }

  // ---- lin1 (fused bias+relu) -> f32 emb in d_out ----
  gemm_nt<2, float><<<g3, 256, 0, stream>>>(regA, PD2, BTl1, PD2, emb, D3, NT, D3, PD2, l1b);

  // ---- lin2 + log_softmax (f32) ----
  head_k<<<(NT + 3) / 4, 256, 0, stream>>>(emb, l2w, l2b, outp);
}

// Round 4
// 2622.128 us; speedup vs baseline: 1.4289x; 1.0512x over previous
//
#include <hip/hip_runtime.h>

#define NT 24264
#define MT 24320      // NT padded to 128-row tiles
#define NDRUG 20000
#define NGENE 4264
#define NE 100000
#define NREL 5
#define IND 1613
#define D1 1340
#define D2 920
#define D3 740
// padded K leading dims (multiples of 32 -> whole BK tiles, 16B-aligned bf16 rows)
#define PIN 1632
#define PD1 1344
#define PD2 928
// concatenated K dims (root + 5 relations)
#define CAT1 (6 * PIN)   // 9792
#define CAT2 (6 * PD1)   // 8064
// padded N row counts for transposed-weight buffers (multiples of 128)
#define ND1 1408
#define ND2 1024
#define ND3 768

typedef unsigned short u16;
typedef unsigned int u32;
typedef short bf16x8 __attribute__((ext_vector_type(8)));
typedef float f32x4 __attribute__((ext_vector_type(4)));

__device__ __forceinline__ u16 f2bf(float f) {
  u32 u = __builtin_bit_cast(u32, f);
  u32 r = (u + 0x7FFFu + ((u >> 16) & 1u)) >> 16;  // RNE
  return (u16)r;
}
__device__ __forceinline__ float bf2f(u16 h) {
  u32 u = ((u32)h) << 16;
  return __builtin_bit_cast(float, u);
}
__device__ __forceinline__ int iclamp(int v, int lo, int hi) {
  return v < lo ? lo : (v > hi ? hi : v);
}

// direct global->LDS DMA, 16B per lane; lds dest must be wave-uniform base
__device__ __forceinline__ void gload_lds16(const u16* g, u16* l) {
  __builtin_amdgcn_global_load_lds(
      (const __attribute__((address_space(1))) unsigned int*)(const void*)g,
      (__attribute__((address_space(3))) unsigned int*)(void*)l,
      16, 0, 0);
}

// bijective XCD-aware tile swizzle (m204): consecutive linear blocks -> same XCD chunk
__device__ __forceinline__ void swz_tile(int& m0, int& n0) {
  const int gx = gridDim.x;
  const int nwg = gx * gridDim.y;
  const int orig = blockIdx.y * gx + blockIdx.x;
  const int q = nwg >> 3, rr = nwg & 7;
  const int xcd = orig & 7, idx = orig >> 3;
  const int nid = (xcd < rr ? xcd * (q + 1) : rr * (q + 1) + (xcd - rr) * q) + idx;
  m0 = (nid / gx) * 128;
  n0 = (nid % gx) * 128;
}

// ---------------- zero int buffer ----------------
__global__ __launch_bounds__(256) void zero_i32_k(int* __restrict__ p, int n) {
  int i = blockIdx.x * 256 + threadIdx.x;
  if (i < n) p[i] = 0;
}

// ---------------- zero pad columns of bf16 [rows][P], cols [D,P) ----------------
__global__ __launch_bounds__(256) void zero_pad_cols_k(u16* __restrict__ h, int D, int P, int rows) {
  int r = blockIdx.x * 256 + threadIdx.x;
  if (r < rows) {
    u16* p = h + (size_t)r * P;
    for (int c = D; c < P; ++c) p[c] = 0;
  }
}

// ---------------- transpose f32 [K][N] -> bf16 [N][ldo], batched ----------------
__global__ __launch_bounds__(256) void transpose_k(
    const float* __restrict__ in, u16* __restrict__ out,
    int K, int N, int ldo, size_t in_batch, size_t out_batch)
{
  __shared__ u16 tile[32][33];
  const int b = blockIdx.z;
  in  += (size_t)b * in_batch;
  out += (size_t)b * out_batch;
  const int n0 = blockIdx.x * 32, k0 = blockIdx.y * 32;
  const int tx = threadIdx.x, ty = threadIdx.y;
  for (int i = ty; i < 32; i += 8) {
    int k = k0 + i, n = n0 + tx;
    tile[i][tx] = (k < K && n < N) ? f2bf(in[(size_t)k * N + n]) : (u16)0;
  }
  __syncthreads();
  for (int i = ty; i < 32; i += 8) {
    int n = n0 + i, k = k0 + tx;
    if (n < N && k < K) out[(size_t)n * ldo + k] = tile[tx][i];
  }
}

// ---------------- h0 = bf16(concat(x, gene_emb)), pad cols zeroed ----------------
__global__ __launch_bounds__(256) void build_h0_k(
    const float* __restrict__ x, const float* __restrict__ gene, u16* __restrict__ h0)
{
  const int row = blockIdx.x;
  const float* s = (row < NDRUG) ? (x + (size_t)row * IND)
                                 : (gene + (size_t)(row - NDRUG) * IND);
  u16* d = h0 + (size_t)row * PIN;
  for (int i = threadIdx.x; i < PIN; i += 256) d[i] = (i < IND) ? f2bf(s[i]) : (u16)0;
}

// ---------------- per-(relation,dst) edge counts (clamped indices) ----------------
__global__ __launch_bounds__(256) void count_k(
    const int* __restrict__ dst, const int* __restrict__ et, int* __restrict__ cnt)
{
  int e = blockIdx.x * 256 + threadIdx.x;
  if (e < NE) {
    int r = iclamp(et[e], 0, NREL - 1);
    int d = iclamp(dst[e], 0, NT - 1);
    atomicAdd(&cnt[(size_t)r * NT + d], 1);
  }
}

// ---------------- dead-simple single-block exclusive scan ----------------
__global__ __launch_bounds__(256) void scan_simple_k(
    const int* __restrict__ in, int* __restrict__ out, int n)
{
  __shared__ int part[256];
  const int tid = threadIdx.x;
  const int chunk = (n + 255) / 256;
  const int lo = tid * chunk;
  const int hi = (lo + chunk < n) ? (lo + chunk) : n;
  int s = 0;
  for (int i = lo; i < hi; ++i) s += in[i];
  part[tid] = s;
  __syncthreads();
  if (tid == 0) {
    int run = 0;
    for (int i = 0; i < 256; ++i) { int t = part[i]; part[i] = run; run += t; }
  }
  __syncthreads();
  int run = part[tid];
  for (int i = lo; i < hi; ++i) { out[i] = run; run += in[i]; }
}

// ---------------- fill CSR edge source list (clamped) ----------------
__global__ __launch_bounds__(256) void fill_k(
    const int* __restrict__ src, const int* __restrict__ dst, const int* __restrict__ et,
    const int* __restrict__ offs, int* __restrict__ pos, int* __restrict__ esrc)
{
  int e = blockIdx.x * 256 + threadIdx.x;
  if (e < NE) {
    int r = iclamp(et[e], 0, NREL - 1);
    int d = iclamp(dst[e], 0, NT - 1);
    int b = r * NT + d;
    int p = offs[b] + atomicAdd(&pos[b], 1);
    p = iclamp(p, 0, NE - 1);
    esrc[p] = iclamp(src[e], 0, NT - 1);
  }
}

// ---------------- gather-mean for one relation (bf16 H -> bf16 out) ----------------
__global__ __launch_bounds__(256) void gather_k(
    const int* __restrict__ esrc, const int* __restrict__ offs, const int* __restrict__ cnt,
    int rel, const u16* __restrict__ H, int ldh, int nvec, u16* __restrict__ out, int ldo)
{
  const int i = blockIdx.x;
  const int b = rel * NT + i;
  int n = iclamp(cnt[b], 0, NE);
  int o = iclamp(offs[b], 0, NE - 1);
  if (o + n > NE) n = NE - o;
  u16* op = out + (size_t)i * ldo;
  if (n <= 0) {
    uint4 z = {0, 0, 0, 0};
    for (int v = threadIdx.x; v < nvec; v += 256) *(uint4*)(op + v * 8) = z;
    return;
  }
  const float inv = 1.0f / (float)n;
  for (int v = threadIdx.x; v < nvec; v += 256) {
    float acc[8] = {};
    for (int e = 0; e < n; ++e) {
      int si = iclamp(esrc[o + e], 0, NT - 1);
      const u16* hp = H + (size_t)si * ldh + v * 8;
      uint4 xv = *(const uint4*)hp;
      const u16* xu = (const u16*)&xv;
      #pragma unroll
      for (int j = 0; j < 8; ++j) acc[j] += bf2f(xu[j]);
    }
    u16 r[8];
    #pragma unroll
    for (int j = 0; j < 8; ++j) {
      float f = acc[j] * inv;
      f = (f == f) ? f : 0.0f;
      r[j] = f2bf(f);
    }
    *(uint4*)(op + v * 8) = *(uint4*)r;
  }
}

// ---------------- unified MFMA NT-GEMM, double-buffered LDS (T3 minimal) ----------
// Virtual A = [A0 (K0 cols) | A1 (K1 cols)]; either part optional (K0/K1 == 0).
// OUTK 0: bf16 C; runtime: bias (nullable, add), acc (C += ...), relu (final).
// OUTK 1: f32 C = relu(A.B + bias)  (lin1 -> emb).
// REQUIRES: K0,K1 % 32 == 0; A/BT rows valid up to grid*128 (pads may be garbage;
// isolated to guarded-out C rows/cols).
template <int OUTK>
__global__ __launch_bounds__(256, 2) void gemm_rg(
    const u16* __restrict__ A0, int lda0, int K0,
    const u16* __restrict__ A1, int lda1, int K1,
    const u16* __restrict__ BT, int ldb,
    void* __restrict__ Cv, int ldc,
    int M, int N,
    const float* __restrict__ bias, int acc, int relu)
{
  constexpr int BM = 128, BN = 128, BK = 32;
  __shared__ u16 As[2][BM * BK];   // 2 x 8 KB
  __shared__ u16 Bs[2][BN * BK];   // 2 x 8 KB
  const int tid = threadIdx.x;
  const int lane = tid & 63;
  const int wid = tid >> 6;
  const int wm = wid >> 1, wn = wid & 1;  // 2x2 wave grid, 64x64 per wave
  const int q = lane >> 4, l15 = lane & 15;
  int m0, n0;
  swz_tile(m0, n0);

  // staging geometry: lane l of wave w covers LDS row w*16 + (l>>2), k-slot (l&3)*8
  const int srow = wid * 16 + (lane >> 2);
  const int skk  = (lane & 3) * 8;

  auto stage = [&](int buf, int kt) {
    const int k0 = kt * BK;
    const u16 *glo, *ghi;
    if (k0 < K0) {
      glo = A0 + (size_t)(m0 + srow) * lda0 + (k0 + skk);
      ghi = A0 + (size_t)(m0 + 64 + srow) * lda0 + (k0 + skk);
    } else {
      const int kk = k0 - K0;
      glo = A1 + (size_t)(m0 + srow) * lda1 + (kk + skk);
      ghi = A1 + (size_t)(m0 + 64 + srow) * lda1 + (kk + skk);
    }
    gload_lds16(glo, &As[buf][(wid * 16) * BK]);
    gload_lds16(ghi, &As[buf][(64 + wid * 16) * BK]);
    gload_lds16(BT + (size_t)(n0 + srow) * ldb + (k0 + skk), &Bs[buf][(wid * 16) * BK]);
    gload_lds16(BT + (size_t)(n0 + 64 + srow) * ldb + (k0 + skk), &Bs[buf][(64 + wid * 16) * BK]);
  };

  f32x4 accf[4][4] = {};

  const int ktiles = (K0 + K1) / BK;
  stage(0, 0);
  __syncthreads();           // drains vmcnt(0): tile 0 resident
  int cur = 0;
  for (int kt = 0; kt < ktiles; ++kt) {
    if (kt + 1 < ktiles) stage(cur ^ 1, kt + 1);   // issue BEFORE compute (T3)

    bf16x8 af[4], bfr[4];
    #pragma unroll
    for (int i = 0; i < 4; ++i)
      af[i] = *(const bf16x8*)&As[cur][(wm * 64 + i * 16 + l15) * BK + q * 8];
    #pragma unroll
    for (int j = 0; j < 4; ++j)
      bfr[j] = *(const bf16x8*)&Bs[cur][(wn * 64 + j * 16 + l15) * BK + q * 8];
    #pragma unroll
    for (int i = 0; i < 4; ++i)
      #pragma unroll
      for (int j = 0; j < 4; ++j)
        accf[i][j] = __builtin_amdgcn_mfma_f32_16x16x32_bf16(af[i], bfr[j], accf[i][j], 0, 0, 0);

    __syncthreads();         // one barrier/tile; drains vmcnt (next tile) + lgkm
    cur ^= 1;
  }

  // epilogue: C/D layout col=lane&15, row=quad*4+reg (m89/m91-verified)
  u16* Cb = (u16*)Cv;
  float* Cf = (float*)Cv;
  #pragma unroll
  for (int i = 0; i < 4; ++i) {
    #pragma unroll
    for (int t = 0; t < 4; ++t) {
      const int r = m0 + wm * 64 + i * 16 + q * 4 + t;
      if (r >= M) continue;
      #pragma unroll
      for (int j = 0; j < 4; ++j) {
        const int c = n0 + wn * 64 + j * 16 + l15;
        if (c >= N) continue;
        const size_t idx = (size_t)r * ldc + c;
        float v = accf[i][j][t];
        v = (v == v) ? v : 0.0f;  // NaN scrub
        if (OUTK == 1) {
          float s = v + bias[c];
          s = (s > 0.0f) ? s : 0.0f;
          Cf[idx] = s;
        } else {
          if (bias) v += bias[c];
          if (acc) {
            float c0 = bf2f(Cb[idx]);
            c0 = (c0 == c0) ? c0 : 0.0f;
            v += c0;
          }
          if (relu) v = (v > 0.0f) ? v : 0.0f;
          Cb[idx] = f2bf(v);
        }
      }
    }
  }
}

// ---------------- lin2 + log_softmax: f32 emb -> f32 logits ----------------
__global__ __launch_bounds__(256) void head_k(
    const float* __restrict__ emb,
    const float* __restrict__ w, const float* __restrict__ b, float* __restrict__ out)
{
  const int row = blockIdx.x * 4 + (threadIdx.x >> 6);
  const int lane = threadIdx.x & 63;
  if (row >= NT) return;
  const float* e = emb + (size_t)row * D3;
  float s0 = 0.f, s1 = 0.f;
  for (int k = lane; k < D3; k += 64) {
    float v = e[k];
    s0 += v * w[2 * k];
    s1 += v * w[2 * k + 1];
  }
  #pragma unroll
  for (int off = 32; off > 0; off >>= 1) {
    s0 += __shfl_down(s0, off, 64);
    s1 += __shfl_down(s1, off, 64);
  }
  if (lane == 0) {
    s0 += b[0]; s1 += b[1];
    s0 = (s0 == s0) ? s0 : 0.0f;
    s1 = (s1 == s1) ? s1 : 0.0f;
    float m = fmaxf(s0, s1);
    float lse = m + logf(expf(s0 - m) + expf(s1 - m));
    out[2 * (size_t)row]     = s0 - lse;
    out[2 * (size_t)row + 1] = s1 - lse;
  }
}

extern "C" void kernel_launch(void* const* d_in, const int* in_sizes, int n_in,
                              void* d_out, int out_size, void* d_ws, size_t ws_size,
                              hipStream_t stream)
{
  (void)in_sizes; (void)n_in; (void)out_size;
  const float* x     = (const float*)d_in[0];
  const int*   ei    = (const int*)d_in[1];
  const int*   et    = (const int*)d_in[2];
  const float* gene  = (const float*)d_in[3];
  const float* W1    = (const float*)d_in[4];
  const float* root1 = (const float*)d_in[5];
  const float* b1    = (const float*)d_in[6];
  const float* W2    = (const float*)d_in[7];
  const float* root2 = (const float*)d_in[8];
  const float* b2    = (const float*)d_in[9];
  const float* l1w   = (const float*)d_in[10];
  const float* l1b   = (const float*)d_in[11];
  const float* l2w   = (const float*)d_in[12];
  const float* l2b   = (const float*)d_in[13];
  const int* srcI = ei;
  const int* dstI = ei + NE;

  char* base = (char*)d_ws;
  size_t off = 0;
  auto take = [&](size_t bytes) -> char* {
    char* p = base + off;
    off += (bytes + 255) & ~(size_t)255;
    return p;
  };
  u16* regA = (u16*)take((size_t)MT * PIN * 2);  // h0; later reused as h2
  u16* regC = (u16*)take((size_t)MT * PD1 * 2);  // h1
  int* cnt  = (int*)take((size_t)NREL * NT * 4);
  int* pos  = (int*)take((size_t)NREL * NT * 4);
  int* offs = (int*)take((size_t)NREL * NT * 4);
  int* esrc = (int*)take((size_t)NE * 4);
  char* wz0 = base + off;
  u16* BTcat1 = (u16*)take((size_t)ND1 * CAT1 * 2);  // [root1^T | W1_r^T] K-concat
  u16* BTcat2 = (u16*)take((size_t)ND2 * CAT2 * 2);  // [root2^T | W2_r^T]
  u16* BTl1   = (u16*)take((size_t)ND3 * PD2 * 2);
  char* wz1 = base + off;
  const size_t base_off = off;

  // agg slot region: S slots of [MT][PIN] (PIN covers layer-2's PD1 too)
  const size_t slot_b = (size_t)MT * PIN * 2;
  int S = 0;
  if (ws_size > base_off) S = (int)((ws_size - base_off) / slot_b);
  if (S < 1) return;  // signature: zero output (ws>=271.5MB known, so S>=1)
  if (S > NREL) S = NREL;
  u16* bufX = (u16*)(base + base_off);

  float* outp = (float*)d_out;
  float* emb  = outp + (size_t)NT * 2;

  // ---- CSR build ----
  zero_i32_k<<<(NREL * NT + 255) / 256, 256, 0, stream>>>(cnt, NREL * NT);
  zero_i32_k<<<(NREL * NT + 255) / 256, 256, 0, stream>>>(pos, NREL * NT);
  count_k<<<(NE + 255) / 256, 256, 0, stream>>>(dstI, et, cnt);
  scan_simple_k<<<1, 256, 0, stream>>>(cnt, offs, NREL * NT);
  fill_k<<<(NE + 255) / 256, 256, 0, stream>>>(srcI, dstI, et, offs, pos, esrc);

  // ---- zero whole transposed-weight region (covers K pads + N-pad rows) ----
  {
    size_t wzn = (size_t)(wz1 - wz0) / 4;
    zero_i32_k<<<(int)((wzn + 255) / 256), 256, 0, stream>>>((int*)wz0, (int)wzn);
  }

  // ---- weight transposes (f32 -> bf16) into K-concat layout ----
  dim3 tb(32, 8);
  transpose_k<<<dim3((D1 + 31) / 32, (IND + 31) / 32, 1),    tb, 0, stream>>>(root1, BTcat1, IND, D1, CAT1, 0, 0);
  transpose_k<<<dim3((D1 + 31) / 32, (IND + 31) / 32, NREL), tb, 0, stream>>>(W1, BTcat1 + PIN, IND, D1, CAT1, (size_t)IND * D1, (size_t)PIN);
  transpose_k<<<dim3((D2 + 31) / 32, (D1 + 31) / 32, 1),     tb, 0, stream>>>(root2, BTcat2, D1, D2, CAT2, 0, 0);
  transpose_k<<<dim3((D2 + 31) / 32, (D1 + 31) / 32, NREL),  tb, 0, stream>>>(W2, BTcat2 + PD1, D1, D2, CAT2, (size_t)D1 * D2, (size_t)PD1);
  transpose_k<<<dim3((D3 + 31) / 32, (D2 + 31) / 32, 1),     tb, 0, stream>>>(l1w, BTl1, D2, D3, PD2, 0, 0);

  build_h0_k<<<NT, 256, 0, stream>>>(x, gene, regA);

  dim3 g1((D1 + 127) / 128, (MT + 127) / 128);
  dim3 g2((D2 + 127) / 128, (MT + 127) / 128);
  dim3 g3((D3 + 127) / 128, (MT + 127) / 128);

  // ---- layer 1: h1 = relu([h0 | agg0..agg4] @ [root1;W1] + b1), S-chunked ----
  {
    int done = 0; bool first = true;
    while (done < NREL) {
      const int nc = (NREL - done < S) ? (NREL - done) : S;
      for (int j = 0; j < nc; ++j)
        gather_k<<<NT, 256, 0, stream>>>(esrc, offs, cnt, done + j, regA, PIN, PIN / 8,
                                         bufX + (size_t)j * PIN, nc * PIN);
      const u16* Bp = BTcat1 + (size_t)(first ? 0 : (1 + done)) * PIN;
      gemm_rg<0><<<g1, 256, 0, stream>>>(
          first ? regA : nullptr, PIN, first ? PIN : 0,
          bufX, nc * PIN, nc * PIN, Bp, CAT1, regC, PD1, NT, D1,
          first ? b1 : nullptr, first ? 0 : 1, (done + nc == NREL) ? 1 : 0);
      first = false; done += nc;
    }
    zero_pad_cols_k<<<(NT + 255) / 256, 256, 0, stream>>>(regC, D1, PD1, NT);
  }

  // ---- layer 2: h2 = relu([h1 | agg0..agg4] @ [root2;W2] + b2), S-chunked ----
  {
    int done = 0; bool first = true;
    while (done < NREL) {
      const int nc = (NREL - done < S) ? (NREL - done) : S;
      for (int j = 0; j < nc; ++j)
        gather_k<<<NT, 256, 0, stream>>>(esrc, offs, cnt, done + j, regC, PD1, PD1 / 8,
                                         bufX + (size_t)j * PD1, nc * PD1);
      const u16* Bp = BTcat2 + (size_t)(first ? 0 : (1 + done)) * PD1;
      gemm_rg<0><<<g2, 256, 0, stream>>>(
          first ? regC : nullptr, PD1, first ? PD1 : 0,
          bufX, nc * PD1, nc * PD1, Bp, CAT2, regA, PD2, NT, D2,
          first ? b2 : nullptr, first ? 0 : 1, (done + nc == NREL) ? 1 : 0);
      first = false; done += nc;
    }
    zero_pad_cols_k<<<(NT + 255) / 256, 256, 0, stream>>>(regA, D2, PD2, NT);
  }

  // ---- lin1 (fused bias+relu) -> f32 emb in d_out ----
  gemm_rg<1><<<g3, 256, 0, stream>>>(regA, PD2, PD2, nullptr, 0, 0,
                                     BTl1, PD2, emb, D3, NT, D3, l1b, 0, 1);

  // ---- lin2 + log_softmax (f32) ----
  head_k<<<(NT + 3) / 4, 256, 0, stream>>>(emb, l2w, l2b, outp);
}

// Round 5
// 2471.702 us; speedup vs baseline: 1.5158x; 1.0609x over previous
//
#include <hip/hip_runtime.h>

#define NT 24264
#define MT 24320      // NT padded to 128-row tiles
#define NDRUG 20000
#define NGENE 4264
#define NE 100000
#define NREL 5
#define IND 1613
#define D1 1340
#define D2 920
#define D3 740
// padded K leading dims (multiples of 32 -> whole BK tiles, 16B-aligned bf16 rows)
#define PIN 1632
#define PD1 1344
#define PD2 928
// concatenated K dims (root + 5 relations)
#define CAT1 (6 * PIN)   // 9792
#define CAT2 (6 * PD1)   // 8064
// padded N row counts for transposed-weight buffers (multiples of 128)
#define ND1 1408
#define ND2 1024
#define ND3 768

typedef unsigned short u16;
typedef unsigned int u32;
typedef short bf16x8 __attribute__((ext_vector_type(8)));
typedef float f32x4 __attribute__((ext_vector_type(4)));

__device__ __forceinline__ u16 f2bf(float f) {
  u32 u = __builtin_bit_cast(u32, f);
  u32 r = (u + 0x7FFFu + ((u >> 16) & 1u)) >> 16;  // RNE
  return (u16)r;
}
__device__ __forceinline__ float bf2f(u16 h) {
  u32 u = ((u32)h) << 16;
  return __builtin_bit_cast(float, u);
}
__device__ __forceinline__ int iclamp(int v, int lo, int hi) {
  return v < lo ? lo : (v > hi ? hi : v);
}

// direct global->LDS DMA, 16B per lane; lds dest must be wave-uniform base
__device__ __forceinline__ void gload_lds16(const u16* g, u16* l) {
  __builtin_amdgcn_global_load_lds(
      (const __attribute__((address_space(1))) unsigned int*)(const void*)g,
      (__attribute__((address_space(3))) unsigned int*)(void*)l,
      16, 0, 0);
}

// bijective XCD-aware tile swizzle (m204): consecutive linear blocks -> same XCD chunk
__device__ __forceinline__ void swz_tile(int& m0, int& n0) {
  const int gx = gridDim.x;
  const int nwg = gx * gridDim.y;
  const int orig = blockIdx.y * gx + blockIdx.x;
  const int q = nwg >> 3, rr = nwg & 7;
  const int xcd = orig & 7, idx = orig >> 3;
  const int nid = (xcd < rr ? xcd * (q + 1) : rr * (q + 1) + (xcd - rr) * q) + idx;
  m0 = (nid / gx) * 128;
  n0 = (nid % gx) * 128;
}

// ---------------- zero int buffer ----------------
__global__ __launch_bounds__(256) void zero_i32_k(int* __restrict__ p, int n) {
  int i = blockIdx.x * 256 + threadIdx.x;
  if (i < n) p[i] = 0;
}

// ---------------- zero pad columns of bf16 [rows][P], cols [D,P) ----------------
__global__ __launch_bounds__(256) void zero_pad_cols_k(u16* __restrict__ h, int D, int P, int rows) {
  int r = blockIdx.x * 256 + threadIdx.x;
  if (r < rows) {
    u16* p = h + (size_t)r * P;
    for (int c = D; c < P; ++c) p[c] = 0;
  }
}

// ---------------- transpose f32 [K][N] -> bf16 [N][ldo], batched ----------------
__global__ __launch_bounds__(256) void transpose_k(
    const float* __restrict__ in, u16* __restrict__ out,
    int K, int N, int ldo, size_t in_batch, size_t out_batch)
{
  __shared__ u16 tile[32][33];
  const int b = blockIdx.z;
  in  += (size_t)b * in_batch;
  out += (size_t)b * out_batch;
  const int n0 = blockIdx.x * 32, k0 = blockIdx.y * 32;
  const int tx = threadIdx.x, ty = threadIdx.y;
  for (int i = ty; i < 32; i += 8) {
    int k = k0 + i, n = n0 + tx;
    tile[i][tx] = (k < K && n < N) ? f2bf(in[(size_t)k * N + n]) : (u16)0;
  }
  __syncthreads();
  for (int i = ty; i < 32; i += 8) {
    int n = n0 + i, k = k0 + tx;
    if (n < N && k < K) out[(size_t)n * ldo + k] = tile[tx][i];
  }
}

// ---------------- h0 = bf16(concat(x, gene_emb)), pad cols zeroed ----------------
__global__ __launch_bounds__(256) void build_h0_k(
    const float* __restrict__ x, const float* __restrict__ gene, u16* __restrict__ h0)
{
  const int row = blockIdx.x;
  const float* s = (row < NDRUG) ? (x + (size_t)row * IND)
                                 : (gene + (size_t)(row - NDRUG) * IND);
  u16* d = h0 + (size_t)row * PIN;
  for (int i = threadIdx.x; i < PIN; i += 256) d[i] = (i < IND) ? f2bf(s[i]) : (u16)0;
}

// ---------------- per-(relation,dst) edge counts (clamped indices) ----------------
__global__ __launch_bounds__(256) void count_k(
    const int* __restrict__ dst, const int* __restrict__ et, int* __restrict__ cnt)
{
  int e = blockIdx.x * 256 + threadIdx.x;
  if (e < NE) {
    int r = iclamp(et[e], 0, NREL - 1);
    int d = iclamp(dst[e], 0, NT - 1);
    atomicAdd(&cnt[(size_t)r * NT + d], 1);
  }
}

// ---------------- dead-simple single-block exclusive scan ----------------
__global__ __launch_bounds__(256) void scan_simple_k(
    const int* __restrict__ in, int* __restrict__ out, int n)
{
  __shared__ int part[256];
  const int tid = threadIdx.x;
  const int chunk = (n + 255) / 256;
  const int lo = tid * chunk;
  const int hi = (lo + chunk < n) ? (lo + chunk) : n;
  int s = 0;
  for (int i = lo; i < hi; ++i) s += in[i];
  part[tid] = s;
  __syncthreads();
  if (tid == 0) {
    int run = 0;
    for (int i = 0; i < 256; ++i) { int t = part[i]; part[i] = run; run += t; }
  }
  __syncthreads();
  int run = part[tid];
  for (int i = lo; i < hi; ++i) { out[i] = run; run += in[i]; }
}

// ---------------- fill CSR edge source list (clamped) ----------------
__global__ __launch_bounds__(256) void fill_k(
    const int* __restrict__ src, const int* __restrict__ dst, const int* __restrict__ et,
    const int* __restrict__ offs, int* __restrict__ pos, int* __restrict__ esrc)
{
  int e = blockIdx.x * 256 + threadIdx.x;
  if (e < NE) {
    int r = iclamp(et[e], 0, NREL - 1);
    int d = iclamp(dst[e], 0, NT - 1);
    int b = r * NT + d;
    int p = offs[b] + atomicAdd(&pos[b], 1);
    p = iclamp(p, 0, NE - 1);
    esrc[p] = iclamp(src[e], 0, NT - 1);
  }
}

// ---------------- gather-mean for one relation (bf16 H -> bf16 out) ----------------
__global__ __launch_bounds__(256) void gather_k(
    const int* __restrict__ esrc, const int* __restrict__ offs, const int* __restrict__ cnt,
    int rel, const u16* __restrict__ H, int ldh, int nvec, u16* __restrict__ out, int ldo)
{
  const int i = blockIdx.x;
  const int b = rel * NT + i;
  int n = iclamp(cnt[b], 0, NE);
  int o = iclamp(offs[b], 0, NE - 1);
  if (o + n > NE) n = NE - o;
  u16* op = out + (size_t)i * ldo;
  if (n <= 0) {
    uint4 z = {0, 0, 0, 0};
    for (int v = threadIdx.x; v < nvec; v += 256) *(uint4*)(op + v * 8) = z;
    return;
  }
  const float inv = 1.0f / (float)n;
  for (int v = threadIdx.x; v < nvec; v += 256) {
    float acc[8] = {};
    for (int e = 0; e < n; ++e) {
      int si = iclamp(esrc[o + e], 0, NT - 1);
      const u16* hp = H + (size_t)si * ldh + v * 8;
      uint4 xv = *(const uint4*)hp;
      const u16* xu = (const u16*)&xv;
      #pragma unroll
      for (int j = 0; j < 8; ++j) acc[j] += bf2f(xu[j]);
    }
    u16 r[8];
    #pragma unroll
    for (int j = 0; j < 8; ++j) {
      float f = acc[j] * inv;
      f = (f == f) ? f : 0.0f;
      r[j] = f2bf(f);
    }
    *(uint4*)(op + v * 8) = *(uint4*)r;
  }
}

// ---------------- unified MFMA NT-GEMM, depth-3 counted-vmcnt pipeline (T4) -------
// Virtual A = [A0 (K0 cols) | A1 (K1 cols)]; either part optional (K0/K1 == 0).
// OUTK 0: bf16 C; runtime: bias (nullable, add), acc (C += ...), relu (final).
// OUTK 1: f32 C = relu(A.B + bias)  (lin1 -> emb).
// REQUIRES: K0,K1 % 32 == 0; A/BT rows valid up to grid*128 (pads may be garbage;
// isolated to guarded-out C rows/cols).
template <int OUTK>
__global__ __launch_bounds__(256) void gemm_rg(
    const u16* __restrict__ A0, int lda0, int K0,
    const u16* __restrict__ A1, int lda1, int K1,
    const u16* __restrict__ BT, int ldb,
    void* __restrict__ Cv, int ldc,
    int M, int N,
    const float* __restrict__ bias, int acc, int relu)
{
  constexpr int BM = 128, BN = 128, BK = 32;
  __shared__ u16 As[3][BM * BK];   // 3 x 8 KB
  __shared__ u16 Bs[3][BN * BK];   // 3 x 8 KB  (48 KB total -> 3 blocks/CU LDS cap)
  const int tid = threadIdx.x;
  const int lane = tid & 63;
  const int wid = tid >> 6;
  const int wm = wid >> 1, wn = wid & 1;  // 2x2 wave grid, 64x64 per wave
  const int q = lane >> 4, l15 = lane & 15;
  int m0, n0;
  swz_tile(m0, n0);

  // staging geometry: lane l of wave w covers LDS row w*16 + (l>>2), k-slot (l&3)*8
  const int srow = wid * 16 + (lane >> 2);
  const int skk  = (lane & 3) * 8;

  auto stage = [&](int buf, int kt) {
    const int k0 = kt * BK;
    const u16 *glo, *ghi;
    if (k0 < K0) {
      glo = A0 + (size_t)(m0 + srow) * lda0 + (k0 + skk);
      ghi = A0 + (size_t)(m0 + 64 + srow) * lda0 + (k0 + skk);
    } else {
      const int kk = k0 - K0;
      glo = A1 + (size_t)(m0 + srow) * lda1 + (kk + skk);
      ghi = A1 + (size_t)(m0 + 64 + srow) * lda1 + (kk + skk);
    }
    gload_lds16(glo, &As[buf][(wid * 16) * BK]);
    gload_lds16(ghi, &As[buf][(64 + wid * 16) * BK]);
    gload_lds16(BT + (size_t)(n0 + srow) * ldb + (k0 + skk), &Bs[buf][(wid * 16) * BK]);
    gload_lds16(BT + (size_t)(n0 + 64 + srow) * ldb + (k0 + skk), &Bs[buf][(64 + wid * 16) * BK]);
  };

  f32x4 accf[4][4] = {};

  const int ktiles = (K0 + K1) / BK;
  // prologue: stage up to 3 tiles (4 loads each, 16B/lane)
  for (int t = 0; t < 3 && t < ktiles; ++t) stage(t, t);

  int buf = 0;
  for (int kt = 0; kt < ktiles; ++kt) {
    // wait for tile kt's 4 loads (per wave), leaving newer tiles in flight.
    if (kt < ktiles - 2)       asm volatile("s_waitcnt vmcnt(8)" ::: "memory");
    else if (kt == ktiles - 2) asm volatile("s_waitcnt vmcnt(4)" ::: "memory");
    else                       asm volatile("s_waitcnt vmcnt(0)" ::: "memory");
    __builtin_amdgcn_s_barrier();     // all waves' tile-kt loads retired -> LDS ready
    __builtin_amdgcn_sched_barrier(0);

    bf16x8 af[4], bfr[4];
    #pragma unroll
    for (int i = 0; i < 4; ++i)
      af[i] = *(const bf16x8*)&As[buf][(wm * 64 + i * 16 + l15) * BK + q * 8];
    #pragma unroll
    for (int j = 0; j < 4; ++j)
      bfr[j] = *(const bf16x8*)&Bs[buf][(wn * 64 + j * 16 + l15) * BK + q * 8];
    #pragma unroll
    for (int i = 0; i < 4; ++i)
      #pragma unroll
      for (int j = 0; j < 4; ++j)
        accf[i][j] = __builtin_amdgcn_mfma_f32_16x16x32_bf16(af[i], bfr[j], accf[i][j], 0, 0, 0);

    __builtin_amdgcn_s_barrier();     // all waves done reading buf
    __builtin_amdgcn_sched_barrier(0);
    if (kt + 3 < ktiles) stage(buf, kt + 3);   // refill freed buffer; vmcnt stays >0
    buf = (buf == 2) ? 0 : buf + 1;
  }

  // epilogue: C/D layout col=lane&15, row=quad*4+reg (m89/m91-verified)
  u16* Cb = (u16*)Cv;
  float* Cf = (float*)Cv;
  #pragma unroll
  for (int i = 0; i < 4; ++i) {
    #pragma unroll
    for (int t = 0; t < 4; ++t) {
      const int r = m0 + wm * 64 + i * 16 + q * 4 + t;
      if (r >= M) continue;
      #pragma unroll
      for (int j = 0; j < 4; ++j) {
        const int c = n0 + wn * 64 + j * 16 + l15;
        if (c >= N) continue;
        const size_t idx = (size_t)r * ldc + c;
        float v = accf[i][j][t];
        v = (v == v) ? v : 0.0f;  // NaN scrub
        if (OUTK == 1) {
          float s = v + bias[c];
          s = (s > 0.0f) ? s : 0.0f;
          Cf[idx] = s;
        } else {
          if (bias) v += bias[c];
          if (acc) {
            float c0 = bf2f(Cb[idx]);
            c0 = (c0 == c0) ? c0 : 0.0f;
            v += c0;
          }
          if (relu) v = (v > 0.0f) ? v : 0.0f;
          Cb[idx] = f2bf(v);
        }
      }
    }
  }
}

// ---------------- lin2 + log_softmax: f32 emb -> f32 logits ----------------
__global__ __launch_bounds__(256) void head_k(
    const float* __restrict__ emb,
    const float* __restrict__ w, const float* __restrict__ b, float* __restrict__ out)
{
  const int row = blockIdx.x * 4 + (threadIdx.x >> 6);
  const int lane = threadIdx.x & 63;
  if (row >= NT) return;
  const float* e = emb + (size_t)row * D3;
  float s0 = 0.f, s1 = 0.f;
  for (int k = lane; k < D3; k += 64) {
    float v = e[k];
    s0 += v * w[2 * k];
    s1 += v * w[2 * k + 1];
  }
  #pragma unroll
  for (int off = 32; off > 0; off >>= 1) {
    s0 += __shfl_down(s0, off, 64);
    s1 += __shfl_down(s1, off, 64);
  }
  if (lane == 0) {
    s0 += b[0]; s1 += b[1];
    s0 = (s0 == s0) ? s0 : 0.0f;
    s1 = (s1 == s1) ? s1 : 0.0f;
    float m = fmaxf(s0, s1);
    float lse = m + logf(expf(s0 - m) + expf(s1 - m));
    out[2 * (size_t)row]     = s0 - lse;
    out[2 * (size_t)row + 1] = s1 - lse;
  }
}

extern "C" void kernel_launch(void* const* d_in, const int* in_sizes, int n_in,
                              void* d_out, int out_size, void* d_ws, size_t ws_size,
                              hipStream_t stream)
{
  (void)in_sizes; (void)n_in; (void)out_size;
  const float* x     = (const float*)d_in[0];
  const int*   ei    = (const int*)d_in[1];
  const int*   et    = (const int*)d_in[2];
  const float* gene  = (const float*)d_in[3];
  const float* W1    = (const float*)d_in[4];
  const float* root1 = (const float*)d_in[5];
  const float* b1    = (const float*)d_in[6];
  const float* W2    = (const float*)d_in[7];
  const float* root2 = (const float*)d_in[8];
  const float* b2    = (const float*)d_in[9];
  const float* l1w   = (const float*)d_in[10];
  const float* l1b   = (const float*)d_in[11];
  const float* l2w   = (const float*)d_in[12];
  const float* l2b   = (const float*)d_in[13];
  const int* srcI = ei;
  const int* dstI = ei + NE;

  char* base = (char*)d_ws;
  size_t off = 0;
  auto take = [&](size_t bytes) -> char* {
    char* p = base + off;
    off += (bytes + 255) & ~(size_t)255;
    return p;
  };
  u16* regA = (u16*)take((size_t)MT * PIN * 2);  // h0; later reused as h2
  u16* regC = (u16*)take((size_t)MT * PD1 * 2);  // h1
  int* cnt  = (int*)take((size_t)NREL * NT * 4);
  int* pos  = (int*)take((size_t)NREL * NT * 4);
  int* offs = (int*)take((size_t)NREL * NT * 4);
  int* esrc = (int*)take((size_t)NE * 4);
  char* wz0 = base + off;
  u16* BTcat1 = (u16*)take((size_t)ND1 * CAT1 * 2);  // [root1^T | W1_r^T] K-concat
  u16* BTcat2 = (u16*)take((size_t)ND2 * CAT2 * 2);  // [root2^T | W2_r^T]
  u16* BTl1   = (u16*)take((size_t)ND3 * PD2 * 2);
  char* wz1 = base + off;
  const size_t base_off = off;

  // agg slot region: S slots of [MT][PIN] (PIN covers layer-2's PD1 too)
  const size_t slot_b = (size_t)MT * PIN * 2;
  int S = 0;
  if (ws_size > base_off) S = (int)((ws_size - base_off) / slot_b);
  if (S < 1) return;  // signature: zero output (ws>=271.5MB known, so S>=1)
  if (S > NREL) S = NREL;
  u16* bufX = (u16*)(base + base_off);

  float* outp = (float*)d_out;
  float* emb  = outp + (size_t)NT * 2;

  // ---- CSR build ----
  zero_i32_k<<<(NREL * NT + 255) / 256, 256, 0, stream>>>(cnt, NREL * NT);
  zero_i32_k<<<(NREL * NT + 255) / 256, 256, 0, stream>>>(pos, NREL * NT);
  count_k<<<(NE + 255) / 256, 256, 0, stream>>>(dstI, et, cnt);
  scan_simple_k<<<1, 256, 0, stream>>>(cnt, offs, NREL * NT);
  fill_k<<<(NE + 255) / 256, 256, 0, stream>>>(srcI, dstI, et, offs, pos, esrc);

  // ---- zero whole transposed-weight region (covers K pads + N-pad rows) ----
  {
    size_t wzn = (size_t)(wz1 - wz0) / 4;
    zero_i32_k<<<(int)((wzn + 255) / 256), 256, 0, stream>>>((int*)wz0, (int)wzn);
  }

  // ---- weight transposes (f32 -> bf16) into K-concat layout ----
  dim3 tb(32, 8);
  transpose_k<<<dim3((D1 + 31) / 32, (IND + 31) / 32, 1),    tb, 0, stream>>>(root1, BTcat1, IND, D1, CAT1, 0, 0);
  transpose_k<<<dim3((D1 + 31) / 32, (IND + 31) / 32, NREL), tb, 0, stream>>>(W1, BTcat1 + PIN, IND, D1, CAT1, (size_t)IND * D1, (size_t)PIN);
  transpose_k<<<dim3((D2 + 31) / 32, (D1 + 31) / 32, 1),     tb, 0, stream>>>(root2, BTcat2, D1, D2, CAT2, 0, 0);
  transpose_k<<<dim3((D2 + 31) / 32, (D1 + 31) / 32, NREL),  tb, 0, stream>>>(W2, BTcat2 + PD1, D1, D2, CAT2, (size_t)D1 * D2, (size_t)PD1);
  transpose_k<<<dim3((D3 + 31) / 32, (D2 + 31) / 32, 1),     tb, 0, stream>>>(l1w, BTl1, D2, D3, PD2, 0, 0);

  build_h0_k<<<NT, 256, 0, stream>>>(x, gene, regA);

  dim3 g1((D1 + 127) / 128, (MT + 127) / 128);
  dim3 g2((D2 + 127) / 128, (MT + 127) / 128);
  dim3 g3((D3 + 127) / 128, (MT + 127) / 128);

  // ---- layer 1: h1 = relu([h0 | agg0..agg4] @ [root1;W1] + b1), S-chunked ----
  {
    int done = 0; bool first = true;
    while (done < NREL) {
      const int nc = (NREL - done < S) ? (NREL - done) : S;
      for (int j = 0; j < nc; ++j)
        gather_k<<<NT, 256, 0, stream>>>(esrc, offs, cnt, done + j, regA, PIN, PIN / 8,
                                         bufX + (size_t)j * PIN, nc * PIN);
      const u16* Bp = BTcat1 + (size_t)(first ? 0 : (1 + done)) * PIN;
      gemm_rg<0><<<g1, 256, 0, stream>>>(
          first ? regA : nullptr, PIN, first ? PIN : 0,
          bufX, nc * PIN, nc * PIN, Bp, CAT1, regC, PD1, NT, D1,
          first ? b1 : nullptr, first ? 0 : 1, (done + nc == NREL) ? 1 : 0);
      first = false; done += nc;
    }
    zero_pad_cols_k<<<(NT + 255) / 256, 256, 0, stream>>>(regC, D1, PD1, NT);
  }

  // ---- layer 2: h2 = relu([h1 | agg0..agg4] @ [root2;W2] + b2), S-chunked ----
  {
    int done = 0; bool first = true;
    while (done < NREL) {
      const int nc = (NREL - done < S) ? (NREL - done) : S;
      for (int j = 0; j < nc; ++j)
        gather_k<<<NT, 256, 0, stream>>>(esrc, offs, cnt, done + j, regC, PD1, PD1 / 8,
                                         bufX + (size_t)j * PD1, nc * PD1);
      const u16* Bp = BTcat2 + (size_t)(first ? 0 : (1 + done)) * PD1;
      gemm_rg<0><<<g2, 256, 0, stream>>>(
          first ? regC : nullptr, PD1, first ? PD1 : 0,
          bufX, nc * PD1, nc * PD1, Bp, CAT2, regA, PD2, NT, D2,
          first ? b2 : nullptr, first ? 0 : 1, (done + nc == NREL) ? 1 : 0);
      first = false; done += nc;
    }
    zero_pad_cols_k<<<(NT + 255) / 256, 256, 0, stream>>>(regA, D2, PD2, NT);
  }

  // ---- lin1 (fused bias+relu) -> f32 emb in d_out ----
  gemm_rg<1><<<g3, 256, 0, stream>>>(regA, PD2, PD2, nullptr, 0, 0,
                                     BTl1, PD2, emb, D3, NT, D3, l1b, 0, 1);

  // ---- lin2 + log_softmax (f32) ----
  head_k<<<(NT + 3) / 4, 256, 0, stream>>>(emb, l2w, l2b, outp);
}